// Round 7
// baseline (4615.659 us; speedup 1.0000x reference)
//
#include <hip/hip_runtime.h>

// Persistent 2-layer GRU. Round-7: direct-fragment loads.
// The LDS staging round-trip (IC load -> LDS write -> barrier -> ds_read) is
// deleted: each wave loads its MFMA A-fragments DIRECTLY from the global bf16
// h slot (row=lane&15(+16), 16B at k-offset), 64x 8B agent loads per lane,
// batch-issued then consumed (compiler inserts the waitcnt before first use).
// Sync protocol = round-5 (proven): spread epoch flags, F0[8]+F1[16],
// L0 waits {F0>=s, F1>=s-3}; L1 waits {F0>=t, F1>=t-1}; 4-deep bf16 rings.
// L0 activation fully in-register (round-6 scheme). L1 keeps shG only.
// All waits have ~100ms timeouts: worst case fast-fail, never a hang.

#define TLEN 512
#define HDIM 512
#define MROW 32
#define NL0  8
#define GRID 192
#define U0   64
#define U1   32
#define HSZE (MROW*HDIM)   // bf16 elems per ring slot (32KB)
#define DEPTH 4

#define RT_BAR 10000000ULL // ~100ms @100MHz realtime clock

typedef __attribute__((ext_vector_type(8))) short bf16x8;
typedef __attribute__((ext_vector_type(4))) float f32x4;
typedef __attribute__((ext_vector_type(2))) unsigned long long u64x2;

#define AT_LD64(p)   __hip_atomic_load((const unsigned long long*)(p), __ATOMIC_RELAXED, __HIP_MEMORY_SCOPE_AGENT)
#define AT_LD32(p)   __hip_atomic_load((const unsigned*)(p), __ATOMIC_RELAXED, __HIP_MEMORY_SCOPE_AGENT)
#define AT_ST16(p,v) __hip_atomic_store((unsigned short*)(p), (v), __ATOMIC_RELAXED, __HIP_MEMORY_SCOPE_AGENT)
#define AT_ST32(p,v) __hip_atomic_store((unsigned*)(p), (v), __ATOMIC_RELAXED, __HIP_MEMORY_SCOPE_AGENT)
#define AT_ST32F(p,v) __hip_atomic_store((float*)(p), (v), __ATOMIC_RELAXED, __HIP_MEMORY_SCOPE_AGENT)

__device__ __forceinline__ unsigned short f2bf(float f){
  unsigned u = __builtin_bit_cast(unsigned, f);
  u = (u + 0x7FFFu + ((u>>16)&1u)) >> 16;   // RNE
  return (unsigned short)u;
}
__device__ __forceinline__ float sigm(float v){ return __builtin_amdgcn_rcpf(1.f + __expf(-v)); }
__device__ __forceinline__ float tanh_f(float v){ return 1.f - 2.f*__builtin_amdgcn_rcpf(__expf(2.f*v)+1.f); }

// Wait until flags[0..7] >= tA and flags[8..23] >= tB (INT_MIN target = skip).
// Flags one-per-64B-line at fl[i*16]. One gather + ballot per poll iteration.
__device__ __forceinline__ bool wait_flags(unsigned* fl, int tA, int tB, int* sab){
  if (threadIdx.x < 64){
    const int lane = threadIdx.x;
    const int tgt = (lane<8) ? tA : (lane<24 ? tB : (int)0x80000000);
    const unsigned long long t0 = __builtin_amdgcn_s_memrealtime();
    int ab = 0;
    for(;;){
      int f = (lane<24) ? (int)AT_LD32(fl + lane*16) : 0x7fffffff;
      if (__ballot(f >= tgt) == ~0ULL) break;
      if (__builtin_amdgcn_s_memrealtime() - t0 > RT_BAR){ ab = 1; break; }
      __builtin_amdgcn_s_sleep(1);
    }
    if (lane==0) *sab = ab;
  }
  __syncthreads();
  __builtin_amdgcn_sched_barrier(0);
  return *sab != 0;
}

extern "C" __global__ void __launch_bounds__(256,1)
gru_persistent(const float* __restrict__ x,
               const float* __restrict__ Wi0,
               const float* __restrict__ bi0,
               const float* __restrict__ Wi1,
               const float* __restrict__ bi1,
               const float* __restrict__ Wh,
               const float* __restrict__ bh,
               const float* __restrict__ fcw,
               const float* __restrict__ fcb,
               float* __restrict__ out,
               unsigned* __restrict__ flg,
               unsigned short* __restrict__ h0g,
               unsigned short* __restrict__ h1g,
               float* __restrict__ h1f)
{
  __shared__ float shG[MROW*192];
  __shared__ int s_ab;

  const int tid  = threadIdx.x;
  const int lane = tid & 63;
  const int w    = tid >> 6;
  const int grp  = blockIdx.x & 7;
  const int wgid = blockIdx.x >> 3;     // 0..23
  const int g32  = grp*32;

  unsigned* fl = flg + grp*512;         // 24 flags, 64B apart; 2KB per group
  unsigned short* h0 = h0g + grp*DEPTH*HSZE;
  unsigned short* h1 = h1g + grp*DEPTH*HSZE;

  const int r0 = lane & 15;             // fragment row (a0); a1 = +16
  const int cb = (lane>>4)*16;          // byte offset within 64B k-block

  if (wgid < NL0){
    // ---------------- layer-0 workgroup: units [u0, u0+64) ----------------
    const int u0  = wgid*U0;
    const int ua2 = w*16 + (lane&15);   // this thread's unit (wave owns 16 units x all 3 gates)

    bf16x8 bfr[3][16];                  // pinned weight fragments; nt == gate
    #pragma unroll
    for (int nt=0; nt<3; ++nt){
      const float* wrow = Wh + (size_t)(nt*HDIM + u0 + ua2)*HDIM;   // Wh[0][gate][unit][:]
      #pragma unroll
      for (int ks=0; ks<16; ++ks){
        int k = ks*32 + (lane>>4)*8;
        const float4 f0 = *(const float4*)(wrow + k);
        const float4 f1 = *(const float4*)(wrow + k + 4);
        bf16x8 v;
        v[0]=(short)f2bf(f0.x); v[1]=(short)f2bf(f0.y); v[2]=(short)f2bf(f0.z); v[3]=(short)f2bf(f0.w);
        v[4]=(short)f2bf(f1.x); v[5]=(short)f2bf(f1.y); v[6]=(short)f2bf(f1.z); v[7]=(short)f2bf(f1.w);
        bfr[nt][ks]=v;
      }
    }
    float wi0v[3], bi0v[3], bh0v[3];
    #pragma unroll
    for (int g=0; g<3; ++g){
      wi0v[g] = Wi0[g*HDIM + u0+ua2];
      bi0v[g] = bi0[g*HDIM + u0+ua2];
      bh0v[g] = bh [g*HDIM + u0+ua2];
    }
    float h_own[8];
    #pragma unroll
    for (int j=0;j<8;++j) h_own[j]=0.f;

    for (int s=0; s<TLEN; ++s){
      // prefetch x (rows b = mt*16 + quad*4 + j), consumed in activation
      float xv[2][4];
      #pragma unroll
      for (int mt=0; mt<2; ++mt)
        #pragma unroll
        for (int j=0;j<4;++j)
          xv[mt][j] = x[(g32 + mt*16 + (lane>>4)*4 + j)*TLEN + s];

      if (wait_flags(fl, s, s-3, &s_ab)) return;

      // direct-fragment loads of h0(s-1): 64 x 8B, batch-issued
      const char* src = (const char*)(h0 + ((s-1)&3)*HSZE);
      unsigned long long hb[64];
      #pragma unroll
      for (int ks=0; ks<16; ++ks){
        const char* p0 = src + r0*1024 + ks*64 + cb;
        const char* p1 = p0 + 16*1024;
        hb[ks*4+0] = AT_LD64(p0);
        hb[ks*4+1] = AT_LD64(p0+8);
        hb[ks*4+2] = AT_LD64(p1);
        hb[ks*4+3] = AT_LD64(p1+8);
      }
      f32x4 acc[2][3] = {};
      #pragma unroll
      for (int ks=0; ks<16; ++ks){
        u64x2 t0; t0[0]=hb[ks*4+0]; t0[1]=hb[ks*4+1];
        u64x2 t1; t1[0]=hb[ks*4+2]; t1[1]=hb[ks*4+3];
        bf16x8 a0 = __builtin_bit_cast(bf16x8, t0);
        bf16x8 a1 = __builtin_bit_cast(bf16x8, t1);
        #pragma unroll
        for (int nt=0; nt<3; ++nt){
          acc[0][nt] = __builtin_amdgcn_mfma_f32_16x16x32_bf16(a0, bfr[nt][ks], acc[0][nt],0,0,0);
          acc[1][nt] = __builtin_amdgcn_mfma_f32_16x16x32_bf16(a1, bfr[nt][ks], acc[1][nt],0,0,0);
        }
      }
      // in-register activation: wave owns all 3 gates of its 16 units
      unsigned short* dst = h0 + (s&3)*HSZE;
      #pragma unroll
      for (int mt=0; mt<2; ++mt)
        #pragma unroll
        for (int j=0;j<4;++j){
          int b = mt*16 + (lane>>4)*4 + j;
          float G0 = acc[mt][0][j] + bh0v[0];
          float G1 = acc[mt][1][j] + bh0v[1];
          float G2 = acc[mt][2][j] + bh0v[2];
          float xvv = xv[mt][j];
          float r_ = sigm(fmaf(xvv, wi0v[0], bi0v[0]) + G0);
          float z_ = sigm(fmaf(xvv, wi0v[1], bi0v[1]) + G1);
          float n_ = tanh_f(fmaf(xvv, wi0v[2], bi0v[2]) + r_*G2);
          float hn = (1.f - z_)*n_ + z_*h_own[mt*4+j];
          h_own[mt*4+j] = hn;
          AT_ST16(&dst[b*HDIM + u0 + ua2], f2bf(hn));
        }
      asm volatile("s_waitcnt vmcnt(0)" ::: "memory");
      __syncthreads();
      if (tid==0) AT_ST32(fl + wgid*16, (unsigned)(s+1));   // publish F0 = s+1
    }
    // final FC: 32 rows x 2 outputs, by wgid-0 WG (F1=TLEN implies h1f stored)
    if (wgid==0){
      if (wait_flags(fl, (int)0x80000000, TLEN, &s_ab)) return;
      int p = tid>>2, kl = tid&3;
      int b = p>>1, o = p&1;
      const char* h8 = (const char*)(h1f + (size_t)(g32+b)*HDIM + kl*128);
      const float2* w2 = (const float2*)(fcw + o*HDIM + kl*128);
      float a2 = 0.f;
      #pragma unroll
      for (int k=0;k<64;++k){
        unsigned long long v = AT_LD64(h8 + k*8);
        float2 hv = __builtin_bit_cast(float2, v);
        float2 wv = w2[k];
        a2 = fmaf(hv.x, wv.x, fmaf(hv.y, wv.y, a2));
      }
      a2 += __shfl_xor(a2, 1);
      a2 += __shfl_xor(a2, 2);
      if (kl==0) out[(g32+b)*2 + o] = a2 + fcb[o];
    }
  } else {
    // ---------------- layer-1 workgroup: units [u1, u1+32) ----------------
    const int u1   = (wgid-NL0)*U1;
    const int colb = (w<2) ? w*48 : 96 + (w-2)*48;  // cols 0..95 gi, 96..191 gh

    bf16x8 bfr[3][16];
    #pragma unroll
    for (int nt=0; nt<3; ++nt){
      int col = colb + nt*16 + (lane&15);
      const float* wrow;
      if (w < 2){ int g = col>>5, uu = col&31;
        wrow = Wi1 + (size_t)(g*HDIM + u1 + uu)*HDIM;             // Wi_rest[0][g][u][:]
      } else {    int c2 = col-96; int g = c2>>5, uu = c2&31;
        wrow = Wh + (size_t)((3+g)*HDIM + u1 + uu)*HDIM;          // Wh[1][g][u][:]
      }
      #pragma unroll
      for (int ks=0; ks<16; ++ks){
        int k = ks*32 + (lane>>4)*8;
        const float4 f0 = *(const float4*)(wrow + k);
        const float4 f1 = *(const float4*)(wrow + k + 4);
        bf16x8 v;
        v[0]=(short)f2bf(f0.x); v[1]=(short)f2bf(f0.y); v[2]=(short)f2bf(f0.z); v[3]=(short)f2bf(f0.w);
        v[4]=(short)f2bf(f1.x); v[5]=(short)f2bf(f1.y); v[6]=(short)f2bf(f1.z); v[7]=(short)f2bf(f1.w);
        bfr[nt][ks]=v;
      }
    }
    const int ua   = tid & 31;
    const int brow = (tid>>5)*4;
    float bi1v[3], bh1v[3];
    #pragma unroll
    for (int g=0; g<3; ++g){
      bi1v[g] = bi1[g*HDIM + u1+ua];
      bh1v[g] = bh [(3+g)*HDIM + u1+ua];
    }
    float h_own[4];
    #pragma unroll
    for (int j=0;j<4;++j) h_own[j]=0.f;

    for (int t=1; t<=TLEN; ++t){
      if (wait_flags(fl, t, t-1, &s_ab)) return;

      // direct-fragment loads: waves 0-1 consume h0(t-1), waves 2-3 h1(t-2)
      const char* srcW = (w<2) ? (const char*)(h0 + ((t-1)&3)*HSZE)
                               : (const char*)(h1 + ((t-2)&3)*HSZE);
      unsigned long long hb[64];
      #pragma unroll
      for (int ks=0; ks<16; ++ks){
        const char* p0 = srcW + r0*1024 + ks*64 + cb;
        const char* p1 = p0 + 16*1024;
        hb[ks*4+0] = AT_LD64(p0);
        hb[ks*4+1] = AT_LD64(p0+8);
        hb[ks*4+2] = AT_LD64(p1);
        hb[ks*4+3] = AT_LD64(p1+8);
      }
      f32x4 acc[2][3] = {};
      #pragma unroll
      for (int ks=0; ks<16; ++ks){
        u64x2 t0; t0[0]=hb[ks*4+0]; t0[1]=hb[ks*4+1];
        u64x2 t1; t1[0]=hb[ks*4+2]; t1[1]=hb[ks*4+3];
        bf16x8 a0 = __builtin_bit_cast(bf16x8, t0);
        bf16x8 a1 = __builtin_bit_cast(bf16x8, t1);
        #pragma unroll
        for (int nt=0; nt<3; ++nt){
          acc[0][nt] = __builtin_amdgcn_mfma_f32_16x16x32_bf16(a0, bfr[nt][ks], acc[0][nt],0,0,0);
          acc[1][nt] = __builtin_amdgcn_mfma_f32_16x16x32_bf16(a1, bfr[nt][ks], acc[1][nt],0,0,0);
        }
      }
      #pragma unroll
      for (int mt=0; mt<2; ++mt)
        #pragma unroll
        for (int nt=0; nt<3; ++nt)
          #pragma unroll
          for (int j=0;j<4;++j){
            int b = mt*16 + (lane>>4)*4 + j;
            shG[b*192 + colb + nt*16 + (lane&15)] = acc[mt][nt][j];
          }
      __syncthreads();
      unsigned short* dstB = h1 + ((t-1)&3)*HSZE;
      #pragma unroll
      for (int j=0;j<4;++j){
        int b = brow + j;
        float gi0 = shG[b*192 + ua]        + bi1v[0];
        float gi1 = shG[b*192 + 32 + ua]   + bi1v[1];
        float gi2 = shG[b*192 + 64 + ua]   + bi1v[2];
        float gh0 = shG[b*192 + 96 + ua]   + bh1v[0];
        float gh1 = shG[b*192 + 128 + ua]  + bh1v[1];
        float gh2 = shG[b*192 + 160 + ua]  + bh1v[2];
        float r_ = sigm(gi0+gh0);
        float z_ = sigm(gi1+gh1);
        float n_ = tanh_f(gi2 + r_*gh2);
        float hn = (1.f - z_)*n_ + z_*h_own[j];
        h_own[j] = hn;
        AT_ST16(&dstB[b*HDIM + u1 + ua], f2bf(hn));
        if (t == TLEN) AT_ST32F(&h1f[(size_t)(g32+b)*HDIM + u1 + ua], hn);
      }
      asm volatile("s_waitcnt vmcnt(0)" ::: "memory");
      __syncthreads();
      if (tid==0) AT_ST32(fl + wgid*16, (unsigned)t);       // publish F1 = t
    }
  }
}

extern "C" void kernel_launch(void* const* d_in, const int* in_sizes, int n_in,
                              void* d_out, int out_size, void* d_ws, size_t ws_size,
                              hipStream_t stream)
{
  const float* x   = (const float*)d_in[0];
  const float* Wi0 = (const float*)d_in[1];
  const float* bi0 = (const float*)d_in[2];
  const float* Wi1 = (const float*)d_in[3];
  const float* bi1 = (const float*)d_in[4];
  const float* Wh  = (const float*)d_in[5];
  const float* bh  = (const float*)d_in[6];
  const float* fcw = (const float*)d_in[7];
  const float* fcb = (const float*)d_in[8];
  float* out = (float*)d_out;

  // ws layout: [0,16384) spread flags | h0 rings (8 grp x 4 x 32KB = 1MB) |
  //            h1 rings (1MB) | fp32 h1_final (512KB)
  unsigned*       flg = (unsigned*)d_ws;
  unsigned short* h0g = (unsigned short*)((char*)d_ws + 16384);
  unsigned short* h1g = (unsigned short*)((char*)d_ws + 16384 + 1048576);
  float*          h1f = (float*)((char*)d_ws + 16384 + 2*1048576);

  hipMemsetAsync(d_ws, 0, 16384 + 2*1048576 + 524288, stream);
  gru_persistent<<<GRID, 256, 0, stream>>>(x,Wi0,bi0,Wi1,bi1,Wh,bh,fcw,fcb,out,
                                           flg,h0g,h1g,h1f);
}

// Round 9
// 2056.446 us; speedup vs baseline: 2.2445x; 2.2445x over previous
//
#include <hip/hip_runtime.h>

// Persistent 2-layer GRU. Round-9: hardware co-residency overlap.
// Protocol = round-5 exactly (agent-scope stores/loads, spread epoch flags,
// F0[8]+F1[16], split-wait L1 staging, 4-deep rings) — only the SHAPE changes:
// 16 groups x 16 batch rows (was 8 x 32), GRID=384, LDS ~46KB, 2 WGs/CU
// (__launch_bounds__(256,2)). While one WG sleeps in its flag poll, the
// co-resident WG (an independent group) computes -> IC wait hides under
// partner compute. Odd groups start ~2us skewed to seed anti-phase.
// All waits have ~100ms timeouts: worst case fast-fail, never a hang.

#define TLEN 512
#define HDIM 512
#define MROW 16
#define NL0  8
#define NGRP 16
#define GRID 384
#define U0   64
#define U1   32
#define HSZE (MROW*HDIM)   // bf16 elems per ring slot (16KB)
#define ROWB 1040          // LDS row stride bytes (1024B data + 16B pad)
#define DEPTH 4

#define RT_BAR 10000000ULL // ~100ms @100MHz realtime clock

typedef __attribute__((ext_vector_type(8))) short bf16x8;
typedef __attribute__((ext_vector_type(4))) float f32x4;

#define AT_LD64(p)   __hip_atomic_load((const unsigned long long*)(p), __ATOMIC_RELAXED, __HIP_MEMORY_SCOPE_AGENT)
#define AT_LD32(p)   __hip_atomic_load((const unsigned*)(p), __ATOMIC_RELAXED, __HIP_MEMORY_SCOPE_AGENT)
#define AT_ST16(p,v) __hip_atomic_store((unsigned short*)(p), (v), __ATOMIC_RELAXED, __HIP_MEMORY_SCOPE_AGENT)
#define AT_ST32(p,v) __hip_atomic_store((unsigned*)(p), (v), __ATOMIC_RELAXED, __HIP_MEMORY_SCOPE_AGENT)
#define AT_ST32F(p,v) __hip_atomic_store((float*)(p), (v), __ATOMIC_RELAXED, __HIP_MEMORY_SCOPE_AGENT)

__device__ __forceinline__ unsigned short f2bf(float f){
  unsigned u = __builtin_bit_cast(unsigned, f);
  u = (u + 0x7FFFu + ((u>>16)&1u)) >> 16;   // RNE
  return (unsigned short)u;
}
__device__ __forceinline__ float sigm(float v){ return __builtin_amdgcn_rcpf(1.f + __expf(-v)); }
__device__ __forceinline__ float tanh_f(float v){ return 1.f - 2.f*__builtin_amdgcn_rcpf(__expf(2.f*v)+1.f); }

// Wait until flags[0..7] >= tA and flags[8..23] >= tB (0x80000000 = skip).
// Flags one per 64B line at fl[i*16]. One gather + ballot per poll iteration.
__device__ __forceinline__ bool wait_flags(unsigned* fl, int tA, int tB, int* sab){
  if (threadIdx.x < 64){
    const int lane = threadIdx.x;
    const int tgt = (lane<8) ? tA : (lane<24 ? tB : (int)0x80000000);
    const unsigned long long t0 = __builtin_amdgcn_s_memrealtime();
    int ab = 0;
    for(;;){
      int f = (lane<24) ? (int)AT_LD32(fl + lane*16) : 0x7fffffff;
      if (__ballot(f >= tgt) == ~0ULL) break;
      if (__builtin_amdgcn_s_memrealtime() - t0 > RT_BAR){ ab = 1; break; }
      __builtin_amdgcn_s_sleep(1);
    }
    if (lane==0) *sab = ab;
  }
  __syncthreads();
  __builtin_amdgcn_sched_barrier(0);
  return *sab != 0;
}

// Stage a 16-row (16KB) slot: 8 x 8B per thread, coalesced.
__device__ __forceinline__ void stage8(const unsigned short* src, unsigned short* shDst, int tid){
  unsigned long long hb[8];
  #pragma unroll
  for (int i=0;i<8;++i)
    hb[i] = AT_LD64((const char*)src + tid*8 + i*2048);
  #pragma unroll
  for (int i=0;i<8;++i){
    int flat = tid*8 + i*2048;
    *(unsigned long long*)((char*)shDst + (flat>>10)*ROWB + (flat&1023)) = hb[i];
  }
}

extern "C" __global__ void __launch_bounds__(256,2)
gru_persistent(const float* __restrict__ x,
               const float* __restrict__ Wi0,
               const float* __restrict__ bi0,
               const float* __restrict__ Wi1,
               const float* __restrict__ bi1,
               const float* __restrict__ Wh,
               const float* __restrict__ bh,
               const float* __restrict__ fcw,
               const float* __restrict__ fcb,
               float* __restrict__ out,
               unsigned* __restrict__ flg,
               unsigned short* __restrict__ h0g,
               unsigned short* __restrict__ h1g,
               float* __restrict__ h1f)
{
  __shared__ unsigned short shA[MROW*(ROWB/2)];
  __shared__ unsigned short shB[MROW*(ROWB/2)];
  __shared__ float shG[MROW*192];
  __shared__ int s_ab;

  const int tid  = threadIdx.x;
  const int lane = tid & 63;
  const int w    = tid >> 6;
  const int grp  = blockIdx.x & (NGRP-1);
  const int wgid = blockIdx.x >> 4;     // 0..23
  const int g16  = grp*MROW;

  unsigned* fl = flg + grp*512;         // 24 flags, 64B apart; 2KB per group
  unsigned short* h0 = h0g + grp*DEPTH*HSZE;
  unsigned short* h1 = h1g + grp*DEPTH*HSZE;

  // seed anti-phase: odd groups start ~2us late (one-time, off steady-state path)
  if (grp & 1){
    const unsigned long long t0 = __builtin_amdgcn_s_memrealtime();
    while (__builtin_amdgcn_s_memrealtime() - t0 < 200ULL)
      __builtin_amdgcn_s_sleep(1);
  }

  if (wgid < NL0){
    // ---------------- layer-0 workgroup: units [u0, u0+64) ----------------
    const int u0   = wgid*U0;
    const int colb = w*48;

    bf16x8 bfr[3][16];                   // pinned weight fragments
    #pragma unroll
    for (int nt=0; nt<3; ++nt){
      int col = colb + nt*16 + (lane&15);
      int g = col>>6, uu = col&63;
      const float* wrow = Wh + (size_t)(g*HDIM + u0 + uu)*HDIM;   // Wh[0][g][u][:]
      #pragma unroll
      for (int ks=0; ks<16; ++ks){
        int k = ks*32 + (lane>>4)*8;
        const float4 f0 = *(const float4*)(wrow + k);
        const float4 f1 = *(const float4*)(wrow + k + 4);
        bf16x8 v;
        v[0]=(short)f2bf(f0.x); v[1]=(short)f2bf(f0.y); v[2]=(short)f2bf(f0.z); v[3]=(short)f2bf(f0.w);
        v[4]=(short)f2bf(f1.x); v[5]=(short)f2bf(f1.y); v[6]=(short)f2bf(f1.z); v[7]=(short)f2bf(f1.w);
        bfr[nt][ks]=v;
      }
    }
    const int ua   = tid & 63;
    const int brow = (tid>>6)*4;         // 4 waves x 4 rows = 16
    float wi0v[3], bi0v[3], bh0v[3];
    #pragma unroll
    for (int g=0; g<3; ++g){
      wi0v[g] = Wi0[g*HDIM + u0+ua];
      bi0v[g] = bi0[g*HDIM + u0+ua];
      bh0v[g] = bh [g*HDIM + u0+ua];
    }
    float h_own[4];
    #pragma unroll
    for (int j=0;j<4;++j) h_own[j]=0.f;

    for (int s=0; s<TLEN; ++s){
      // prefetch x (hidden under the flag wait)
      float xv[4];
      #pragma unroll
      for (int j=0;j<4;++j) xv[j] = x[(g16+brow+j)*TLEN + s];

      // need h0(s-1) complete (F0>=s); ring slot s&3 reader-free (F1>=s-3)
      if (wait_flags(fl, s, s-3, &s_ab)) return;

      stage8(h0 + ((s-1)&3)*HSZE, shA, tid);
      __syncthreads();
      f32x4 acc[3] = {};
      #pragma unroll
      for (int ks=0; ks<16; ++ks){
        int koff = ks*64 + (lane>>4)*16;
        bf16x8 a0 = *(const bf16x8*)((const char*)shA + (lane&15)*ROWB + koff);
        #pragma unroll
        for (int nt=0; nt<3; ++nt)
          acc[nt] = __builtin_amdgcn_mfma_f32_16x16x32_bf16(a0, bfr[nt][ks], acc[nt],0,0,0);
      }
      #pragma unroll
      for (int nt=0; nt<3; ++nt)
        #pragma unroll
        for (int j=0;j<4;++j){
          int b = (lane>>4)*4 + j;
          shG[b*192 + colb + nt*16 + (lane&15)] = acc[nt][j];
        }
      __syncthreads();
      unsigned short* dstA = h0 + (s&3)*HSZE;
      #pragma unroll
      for (int j=0;j<4;++j){
        int b = brow + j;
        float G0 = shG[b*192 + ua]       + bh0v[0];
        float G1 = shG[b*192 + 64 + ua]  + bh0v[1];
        float G2 = shG[b*192 + 128 + ua] + bh0v[2];
        float r_ = sigm(fmaf(xv[j], wi0v[0], bi0v[0]) + G0);
        float z_ = sigm(fmaf(xv[j], wi0v[1], bi0v[1]) + G1);
        float n_ = tanh_f(fmaf(xv[j], wi0v[2], bi0v[2]) + r_*G2);
        float hn = (1.f - z_)*n_ + z_*h_own[j];
        h_own[j] = hn;
        AT_ST16(&dstA[b*HDIM + u0 + ua], f2bf(hn));
      }
      asm volatile("s_waitcnt vmcnt(0)" ::: "memory");
      __syncthreads();
      if (tid==0) AT_ST32(fl + wgid*16, (unsigned)(s+1));   // publish F0 = s+1
    }
    // final FC: 16 rows x 2 outputs, by wgid-0 WG (F1=TLEN implies h1f stored)
    if (wgid==0){
      if (wait_flags(fl, (int)0x80000000, TLEN, &s_ab)) return;
      if (tid < 128){
        int p = tid>>2, kl = tid&3;
        int b = p>>1, o = p&1;
        const char* h8 = (const char*)(h1f + (size_t)(g16+b)*HDIM + kl*128);
        const float2* w2 = (const float2*)(fcw + o*HDIM + kl*128);
        float a2 = 0.f;
        #pragma unroll
        for (int k=0;k<64;++k){
          unsigned long long v = AT_LD64(h8 + k*8);
          float2 hv = __builtin_bit_cast(float2, v);
          float2 wv = w2[k];
          a2 = fmaf(hv.x, wv.x, fmaf(hv.y, wv.y, a2));
        }
        a2 += __shfl_xor(a2, 1);
        a2 += __shfl_xor(a2, 2);
        if (kl==0) out[(g16+b)*2 + o] = a2 + fcb[o];
      }
    }
  } else {
    // ---------------- layer-1 workgroup: units [u1, u1+32) ----------------
    const int u1   = (wgid-NL0)*U1;
    const int colb = (w<2) ? w*48 : 96 + (w-2)*48;  // cols 0..95 gi, 96..191 gh

    bf16x8 bfr[3][16];
    #pragma unroll
    for (int nt=0; nt<3; ++nt){
      int col = colb + nt*16 + (lane&15);
      const float* wrow;
      if (w < 2){ int g = col>>5, uu = col&31;
        wrow = Wi1 + (size_t)(g*HDIM + u1 + uu)*HDIM;             // Wi_rest[0][g][u][:]
      } else {    int c2 = col-96; int g = c2>>5, uu = c2&31;
        wrow = Wh + (size_t)((3+g)*HDIM + u1 + uu)*HDIM;          // Wh[1][g][u][:]
      }
      #pragma unroll
      for (int ks=0; ks<16; ++ks){
        int k = ks*32 + (lane>>4)*8;
        const float4 f0 = *(const float4*)(wrow + k);
        const float4 f1 = *(const float4*)(wrow + k + 4);
        bf16x8 v;
        v[0]=(short)f2bf(f0.x); v[1]=(short)f2bf(f0.y); v[2]=(short)f2bf(f0.z); v[3]=(short)f2bf(f0.w);
        v[4]=(short)f2bf(f1.x); v[5]=(short)f2bf(f1.y); v[6]=(short)f2bf(f1.z); v[7]=(short)f2bf(f1.w);
        bfr[nt][ks]=v;
      }
    }
    const int ua   = tid & 31;
    const int brow = (tid>>5)*2;        // 8 half-waves x 2 rows = 16
    float bi1v[3], bh1v[3];
    #pragma unroll
    for (int g=0; g<3; ++g){
      bi1v[g] = bi1[g*HDIM + u1+ua];
      bh1v[g] = bh [(3+g)*HDIM + u1+ua];
    }
    float h_own[2];
    #pragma unroll
    for (int j=0;j<2;++j) h_own[j]=0.f;

    for (int t=1; t<=TLEN; ++t){
      const unsigned short* srcA = h0 + ((t-1)&3)*HSZE;   // h0(t-1)
      const unsigned short* srcB = h1 + ((t-2)&3)*HSZE;   // h1(t-2)

      // phase 1: h1(t-2) availability (own-layer crew, usually already set)
      if (wait_flags(fl, (int)0x80000000, t-1, &s_ab)) return;
      unsigned long long hb1[8];
      #pragma unroll
      for (int i=0;i<8;++i)
        hb1[i] = AT_LD64((const char*)srcB + tid*8 + i*2048);

      // phase 2: tight edge (h0(t-1) from L0); h1 loads fly during this wait
      if (wait_flags(fl, t, (int)0x80000000, &s_ab)) return;
      unsigned long long hb0[8];
      #pragma unroll
      for (int i=0;i<8;++i)
        hb0[i] = AT_LD64((const char*)srcA + tid*8 + i*2048);

      #pragma unroll
      for (int i=0;i<8;++i){
        int flat = tid*8 + i*2048;
        *(unsigned long long*)((char*)shA + (flat>>10)*ROWB + (flat&1023)) = hb0[i];
        *(unsigned long long*)((char*)shB + (flat>>10)*ROWB + (flat&1023)) = hb1[i];
      }
      __syncthreads();
      const char* shSrc = (w<2) ? (const char*)shA : (const char*)shB;
      f32x4 acc[3] = {};
      #pragma unroll
      for (int ks=0; ks<16; ++ks){
        int koff = ks*64 + (lane>>4)*16;
        bf16x8 a0 = *(const bf16x8*)(shSrc + (lane&15)*ROWB + koff);
        #pragma unroll
        for (int nt=0; nt<3; ++nt)
          acc[nt] = __builtin_amdgcn_mfma_f32_16x16x32_bf16(a0, bfr[nt][ks], acc[nt],0,0,0);
      }
      #pragma unroll
      for (int nt=0; nt<3; ++nt)
        #pragma unroll
        for (int j=0;j<4;++j){
          int b = (lane>>4)*4 + j;
          shG[b*192 + colb + nt*16 + (lane&15)] = acc[nt][j];
        }
      __syncthreads();
      unsigned short* dstB = h1 + ((t-1)&3)*HSZE;
      #pragma unroll
      for (int j=0;j<2;++j){
        int b = brow + j;
        float gi0 = shG[b*192 + ua]        + bi1v[0];
        float gi1 = shG[b*192 + 32 + ua]   + bi1v[1];
        float gi2 = shG[b*192 + 64 + ua]   + bi1v[2];
        float gh0 = shG[b*192 + 96 + ua]   + bh1v[0];
        float gh1 = shG[b*192 + 128 + ua]  + bh1v[1];
        float gh2 = shG[b*192 + 160 + ua]  + bh1v[2];
        float r_ = sigm(gi0+gh0);
        float z_ = sigm(gi1+gh1);
        float n_ = tanh_f(gi2 + r_*gh2);
        float hn = (1.f - z_)*n_ + z_*h_own[j];
        h_own[j] = hn;
        AT_ST16(&dstB[b*HDIM + u1 + ua], f2bf(hn));
        if (t == TLEN) AT_ST32F(&h1f[(size_t)(g16+b)*HDIM + u1 + ua], hn);
      }
      asm volatile("s_waitcnt vmcnt(0)" ::: "memory");
      __syncthreads();
      if (tid==0) AT_ST32(fl + wgid*16, (unsigned)t);       // publish F1 = t
    }
  }
}

extern "C" void kernel_launch(void* const* d_in, const int* in_sizes, int n_in,
                              void* d_out, int out_size, void* d_ws, size_t ws_size,
                              hipStream_t stream)
{
  const float* x   = (const float*)d_in[0];
  const float* Wi0 = (const float*)d_in[1];
  const float* bi0 = (const float*)d_in[2];
  const float* Wi1 = (const float*)d_in[3];
  const float* bi1 = (const float*)d_in[4];
  const float* Wh  = (const float*)d_in[5];
  const float* bh  = (const float*)d_in[6];
  const float* fcw = (const float*)d_in[7];
  const float* fcb = (const float*)d_in[8];
  float* out = (float*)d_out;

  // ws layout: [0,32K) spread flags (16 grp x 2KB) | h0 rings (16 x 4 x 16KB = 1MB)
  //            | h1 rings (1MB) | fp32 h1_final (512KB)
  unsigned*       flg = (unsigned*)d_ws;
  unsigned short* h0g = (unsigned short*)((char*)d_ws + 32768);
  unsigned short* h1g = (unsigned short*)((char*)d_ws + 32768 + 1048576);
  float*          h1f = (float*)((char*)d_ws + 32768 + 2*1048576);

  hipMemsetAsync(d_ws, 0, 32768 + 2*1048576 + 524288, stream);
  gru_persistent<<<GRID, 256, 0, stream>>>(x,Wi0,bi0,Wi1,bi1,Wh,bh,fcw,fcb,out,
                                           flg,h0g,h1g,h1f);
}